// Round 12
// baseline (1629.393 us; speedup 1.0000x reference)
//
#include <hip/hip_runtime.h>
#include <hip/hip_fp16.h>

#define NV    6890
#define NQ    32768
#define DF    64
#define GS    32
#define NC    (GS * GS * GS)
#define CSZ   0.3125f
#define CINV  3.2f
#define GMIN  (-5.0f)

typedef _Float16 v8h  __attribute__((ext_vector_type(8)));
typedef float    f32x4 __attribute__((ext_vector_type(4)));
typedef unsigned int       u32;
typedef unsigned long long u64;
typedef unsigned short     u16;

// ---- workspace layout (bytes) ----
static constexpr size_t VTX4_OFF   = 0;        // float4[6912] (orig order, for mlp)
static constexpr size_t VSTART_OFF = 110592;   // u32[32769]
static constexpr size_t VCUR_OFF   = 241920;   // u32[32768]
static constexpr size_t QSTART_OFF = 372992;   // u32[32769]  (MORTON bins)
static constexpr size_t QCUR_OFF   = 504320;   // u32[32768]
static constexpr size_t VSORT_OFF  = 635392;   // float4[6912] cell-sorted (row-major)
static constexpr size_t VSID_OFF   = 745984;   // u32[6912] orig ids
static constexpr size_t QSORT_OFF  = 773632;   // float4[32768] {x,y,z,bitcast(m)} Morton-sorted
static constexpr size_t KIDX_OFF   = 1297920;  // int[NQ*8]
static constexpr size_t KW_OFF     = 2346496;  // float[NQ*8]
static constexpr size_t WFRAG_OFF  = 3395072;  // f16[53248]

__device__ __forceinline__ int cellc(float x) {
    int c = (int)floorf((x - GMIN) * CINV);
    return c < 0 ? 0 : (c > GS - 1 ? GS - 1 : c);
}

__device__ __forceinline__ u32 part1by2(u32 v) {
    v &= 0x3FFu;
    v = (v | (v << 16)) & 0x030000FFu;
    v = (v | (v << 8))  & 0x0300F00Fu;
    v = (v | (v << 4))  & 0x030C30C3u;
    v = (v | (v << 2))  & 0x09249249u;
    return v;
}
__device__ __forceinline__ int mortonid(int cx, int cy, int cz) {
    return (int)(part1by2((u32)cx) | (part1by2((u32)cy) << 1) | (part1by2((u32)cz) << 2));
}

// u64 sorted top-8 insert (ascending). Compares precomputed; uses OLD values.
#define KINSERT(nk) do {                                  \
    bool c0 = (nk) < key[0], c1 = (nk) < key[1],          \
         c2 = (nk) < key[2], c3 = (nk) < key[3],          \
         c4 = (nk) < key[4], c5 = (nk) < key[5],          \
         c6 = (nk) < key[6], c7 = (nk) < key[7];          \
    key[7] = c7 ? (c6 ? key[6] : (nk)) : key[7];          \
    key[6] = c6 ? (c5 ? key[5] : (nk)) : key[6];          \
    key[5] = c5 ? (c4 ? key[4] : (nk)) : key[5];          \
    key[4] = c4 ? (c3 ? key[3] : (nk)) : key[4];          \
    key[3] = c3 ? (c2 ? key[2] : (nk)) : key[3];          \
    key[2] = c2 ? (c1 ? key[1] : (nk)) : key[2];          \
    key[1] = c1 ? (c0 ? key[0] : (nk)) : key[1];          \
    key[0] = c0 ? (nk) : key[0];                          \
} while (0)

// Wave-uniform candidate eval: all lanes process vsorted[kk] (scalar stream).
#define CAND(kk) do {                                                         \
    float4 v = vsorted[kk];                                                   \
    float s = fmaf(nqx, v.x, v.w); s = fmaf(nqy, v.y, s); s = fmaf(nqz, v.z, s); \
    u32 u = __float_as_uint(s);                                               \
    u = (u & 0x80000000u) ? ~u : (u | 0x80000000u);                           \
    u64 nk = ((u64)u << 16) | (u64)vsid[kk];                                  \
    if (nk < key[7]) { KINSERT(nk); }                                         \
} while (0)

#define SCANSPAN(a, b) do {                                                   \
    _Pragma("unroll 2")                                                       \
    for (u32 k = (a); k < (b); ++k) { CAND(k); }                              \
} while (0)

// prep: pack vtx4 + vertex(row-major)/query(Morton) histograms + wfrag swizzle.
__global__ void prep_kernel(const float* __restrict__ vtx, float4* __restrict__ vtx4,
                            u32* __restrict__ vstart, u32* __restrict__ qstart,
                            const float* __restrict__ qpts,
                            const float* __restrict__ W0, const float* __restrict__ W1,
                            const float* __restrict__ W2, const float* __restrict__ W3,
                            _Float16* __restrict__ wfrag) {
    int b = blockIdx.x;
    if (b < 27) {
        int i = b * 256 + threadIdx.x;
        if (i < NV) {
            float x = vtx[i * 3 + 0], y = vtx[i * 3 + 1], z = vtx[i * 3 + 2];
            vtx4[i] = make_float4(x, y, z, 0.5f * (x * x + y * y + z * z));
            int cid = (cellc(z) * GS + cellc(y)) * GS + cellc(x);
            atomicAdd(&vstart[cid], 1u);
        }
        return;
    }
    if (b < 155) {
        int i = (b - 27) * 256 + threadIdx.x;
        float x = qpts[i * 3 + 0], y = qpts[i * 3 + 1], z = qpts[i * 3 + 2];
        int mid = mortonid(cellc(x), cellc(y), cellc(z));
        atomicAdd(&qstart[mid], 1u);
        return;
    }
    int e = (b - 155) * 256 + threadIdx.x;   // 0..53247
    const float* W; int base, NCT, C, KD;
    if      (e < 12288) { W = W0; base = 0;     NCT = 8; C = 128; KD = 67;  }
    else if (e < 28672) { W = W1; base = 12288; NCT = 8; C = 128; KD = 128; }
    else if (e < 45056) { W = W2; base = 28672; NCT = 8; C = 128; KD = 128; }
    else                { W = W3; base = 45056; NCT = 4; C = 64;  KD = 128; }
    int le = e - base;
    int t = le >> 9, r = le & 511;
    int lane = r >> 3, j = r & 7;
    int kt = t / NCT, ct = t % NCT;
    int k = kt * 32 + (lane >> 4) * 8 + j;
    int col = ct * 16 + (lane & 15);
    float v = (k < KD) ? W[k * C + col] : 0.0f;
    wfrag[e] = (_Float16)v;
}

// Exclusive scan of both 32768-cell histograms (1 block, 1024 thr, 32 cells/thr,
// uint4-vectorized loads/stores for ILP).
__global__ __launch_bounds__(1024) void scan_kernel(u32* __restrict__ vstart, u32* __restrict__ vcur,
                                                    u32* __restrict__ qstart, u32* __restrict__ qcur) {
    __shared__ u32 wsv[16], wsq[16];
    const int t = threadIdx.x, lane = t & 63, wv = t >> 6;
    u32 va[32], qa[32];
    uint4* vp = (uint4*)(vstart + t * 32);
    uint4* qp = (uint4*)(qstart + t * 32);
#pragma unroll
    for (int i = 0; i < 8; ++i) {
        uint4 x = vp[i];
        va[4 * i] = x.x; va[4 * i + 1] = x.y; va[4 * i + 2] = x.z; va[4 * i + 3] = x.w;
        uint4 y = qp[i];
        qa[4 * i] = y.x; qa[4 * i + 1] = y.y; qa[4 * i + 2] = y.z; qa[4 * i + 3] = y.w;
    }
    u32 vs = 0, qs = 0;
#pragma unroll
    for (int i = 0; i < 32; ++i) {
        u32 tv = va[i]; va[i] = vs; vs += tv;
        u32 tq = qa[i]; qa[i] = qs; qs += tq;
    }
    u32 vinc = vs, qinc = qs;
    for (int d = 1; d < 64; d <<= 1) {
        u32 a = __shfl_up(vinc, d);
        u32 b = __shfl_up(qinc, d);
        if (lane >= d) { vinc += a; qinc += b; }
    }
    if (lane == 63) { wsv[wv] = vinc; wsq[wv] = qinc; }
    __syncthreads();
    u32 vbase = 0, qbase = 0;
    for (int i = 0; i < wv; ++i) { vbase += wsv[i]; qbase += wsq[i]; }
    u32 vexc = vbase + vinc - vs;
    u32 qexc = qbase + qinc - qs;
    uint4* vcp = (uint4*)(vcur + t * 32);
    uint4* qcp = (uint4*)(qcur + t * 32);
#pragma unroll
    for (int i = 0; i < 8; ++i) {
        uint4 x = make_uint4(vexc + va[4 * i], vexc + va[4 * i + 1],
                             vexc + va[4 * i + 2], vexc + va[4 * i + 3]);
        vp[i] = x; vcp[i] = x;
        uint4 y = make_uint4(qexc + qa[4 * i], qexc + qa[4 * i + 1],
                             qexc + qa[4 * i + 2], qexc + qa[4 * i + 3]);
        qp[i] = y; qcp[i] = y;
    }
    if (t == 1023) { vstart[NC] = vexc + vs; qstart[NC] = qexc + qs; }
}

// scatter: blocks [0,27) vertices (row-major bins); [27,155) queries (Morton bins).
__global__ void scatter_kernel(const float* __restrict__ vtx, const float* __restrict__ qpts,
                               u32* __restrict__ vcur, u32* __restrict__ qcur,
                               float4* __restrict__ vsorted, u32* __restrict__ vsid,
                               float4* __restrict__ qsorted) {
    int b = blockIdx.x;
    if (b < 27) {
        int i = b * 256 + threadIdx.x;
        if (i < NV) {
            float x = vtx[i * 3 + 0], y = vtx[i * 3 + 1], z = vtx[i * 3 + 2];
            int cid = (cellc(z) * GS + cellc(y)) * GS + cellc(x);
            u32 pos = atomicAdd(&vcur[cid], 1u);
            vsorted[pos] = make_float4(x, y, z, 0.5f * (x * x + y * y + z * z));
            vsid[pos] = (u32)i;
        }
        return;
    }
    int i = (b - 27) * 256 + threadIdx.x;
    float x = qpts[i * 3 + 0], y = qpts[i * 3 + 1], z = qpts[i * 3 + 2];
    int mid = mortonid(cellc(x), cellc(y), cellc(z));
    u32 pos = atomicAdd(&qcur[mid], 1u);
    qsorted[pos] = make_float4(x, y, z, __int_as_float(i));
}

// Group-box grid KNN over MORTON-sorted queries: one wave per 64 consecutive
// queries (occupied Morton cells are spatially adjacent -> compact boxes even
// in sparse regions). 4 independent waves per block. Wave reduces its queries'
// cell bounding box -> SGPRs, walks Chebyshev rings around the box on the
// ROW-MAJOR vertex grid. Per-slice band emptiness pre-check (2 scalar loads)
// skips empty outskirt slices. Exact: box-ring-R cell has >= R-1 whole cells
// between it and ANY query in the box => unexamined points >= (R-1)*CS away;
// terminate when __all(8 found && d8^2 <= ((R-1)*CS)^2 - eps). Covered-grid
// break. Key=(mono(s)<<16)|id reproduces top_k (distance,index) order.
__global__ __launch_bounds__(256) void knn_kernel(const float4* __restrict__ vsorted,
                                                  const u32* __restrict__ vsid,
                                                  const u32* __restrict__ vstart,
                                                  const float4* __restrict__ qsorted,
                                                  int* __restrict__ kidx,
                                                  float* __restrict__ kw) {
    const int l = threadIdx.x & 63;
    const u32 qi = (blockIdx.x * 4 + (threadIdx.x >> 6)) * 64 + (u32)l;
    float4 qv = qsorted[qi];
    const float qx = qv.x, qy = qv.y, qz = qv.z;
    const int om = __float_as_int(qv.w);
    const float nqx = -qx, nqy = -qy, nqz = -qz;
    const float q2 = fmaf(qx, qx, fmaf(qy, qy, qz * qz));
    const int cx = cellc(qx), cy = cellc(qy), cz = cellc(qz);

    // ---- wave-reduce cell bounding box -> scalar regs ----
    int bx0 = cx, bx1 = cx, by0 = cy, by1 = cy, bz0 = cz, bz1 = cz;
#pragma unroll
    for (int d = 1; d < 64; d <<= 1) {
        int t;
        t = __shfl_xor(bx0, d); bx0 = t < bx0 ? t : bx0;
        t = __shfl_xor(bx1, d); bx1 = t > bx1 ? t : bx1;
        t = __shfl_xor(by0, d); by0 = t < by0 ? t : by0;
        t = __shfl_xor(by1, d); by1 = t > by1 ? t : by1;
        t = __shfl_xor(bz0, d); bz0 = t < bz0 ? t : bz0;
        t = __shfl_xor(bz1, d); bz1 = t > bz1 ? t : bz1;
    }
    bx0 = __builtin_amdgcn_readfirstlane(bx0);
    bx1 = __builtin_amdgcn_readfirstlane(bx1);
    by0 = __builtin_amdgcn_readfirstlane(by0);
    by1 = __builtin_amdgcn_readfirstlane(by1);
    bz0 = __builtin_amdgcn_readfirstlane(bz0);
    bz1 = __builtin_amdgcn_readfirstlane(bz1);

    u64 key[8];
#pragma unroll
    for (int i = 0; i < 8; ++i) key[i] = ~0ull;

#pragma unroll 1
    for (int R = 0; R < GS; ++R) {
        if (R >= 1) {
            bool mydone = false;
            if (key[7] != ~0ull) {
                u32 us = (u32)(key[7] >> 16);
                u32 uo = (us & 0x80000000u) ? (us & 0x7FFFFFFFu) : ~us;
                float s8 = __uint_as_float(uo);
                float d8sq = fmaf(2.0f, s8, q2);
                float bnd = (float)(R - 1) * CSZ;
                mydone = d8sq <= bnd * bnd - 1e-4f;
            }
            if (__all(mydone)) break;
        }
        int z0 = bz0 - R < 0 ? 0 : bz0 - R, z1 = bz1 + R > GS - 1 ? GS - 1 : bz1 + R;
        int y0 = by0 - R < 0 ? 0 : by0 - R, y1 = by1 + R > GS - 1 ? GS - 1 : by1 + R;
#pragma unroll 1
        for (int z = z0; z <= z1; ++z) {
            int adz = bz0 - z > z - bz1 ? bz0 - z : z - bz1; adz = adz < 0 ? 0 : adz;
            // band emptiness pre-check: rows y0..y1, all x of this slice
            u32 band0 = vstart[(z * GS + y0) * GS];
            u32 band1 = vstart[(z * GS + y1 + 1) * GS];
            if (band0 == band1) continue;
#pragma unroll 1
            for (int y = y0; y <= y1; ++y) {
                int ady = by0 - y > y - by1 ? by0 - y : y - by1; ady = ady < 0 ? 0 : ady;
                int rowb = (z * GS + y) * GS;
                if (adz == R || ady == R) {
                    int x0 = bx0 - R < 0 ? 0 : bx0 - R, x1 = bx1 + R > GS - 1 ? GS - 1 : bx1 + R;
                    u32 a = vstart[rowb + x0], bb = vstart[rowb + x1 + 1];
                    SCANSPAN(a, bb);
                } else {
                    if (bx0 - R >= 0) {
                        u32 a = vstart[rowb + bx0 - R], bb = vstart[rowb + bx0 - R + 1];
                        SCANSPAN(a, bb);
                    }
                    if (bx1 + R <= GS - 1) {
                        u32 a = vstart[rowb + bx1 + R], bb = vstart[rowb + bx1 + R + 1];
                        SCANSPAN(a, bb);
                    }
                }
            }
        }
        // whole grid covered by rings 0..R -> nothing left to scan
        if (bz0 - R <= 0 && bz1 + R >= GS - 1 && by0 - R <= 0 && by1 + R >= GS - 1 &&
            bx0 - R <= 0 && bx1 + R >= GS - 1) break;
    }

    float inv[8], ssum = 0.0f;
    int idx8[8];
#pragma unroll
    for (int i = 0; i < 8; ++i) {
        u32 us = (u32)(key[i] >> 16);
        u32 uo = (us & 0x80000000u) ? (us & 0x7FFFFFFFu) : ~us;
        float s = __uint_as_float(uo);
        float dd = fmaf(2.0f, s, q2);
        float d = sqrtf(fmaxf(dd, 0.0f)) + 1e-9f;
        inv[i] = 1.0f / d; ssum += inv[i];
        idx8[i] = (int)(key[i] & 0xFFFFull);
    }
    float rs = 1.0f / ssum;
#pragma unroll
    for (int i = 0; i < 8; ++i) {
        kidx[om * 8 + i] = idx8[i];
        kw[om * 8 + i] = inv[i] * rs;
    }
}

// One MLP layer on this wave's 32 rows, in-place in buf. A-frag: row=l&15(+16*rt),
// k=(l>>4)*8+j; B-frag preswizzled with the SAME (lane,j)->k map (k-perm cancels).
template <int KSTEPS, int NCT, bool RELU>
__device__ __forceinline__ void mlp_layer(_Float16 (*buf)[136],
                                          const _Float16* __restrict__ frag,
                                          const float* __restrict__ bias,
                                          int w, int l) {
    const int cl = l & 15, gl = l >> 4;
    f32x4 acc[2][NCT];
#pragma unroll
    for (int ct = 0; ct < NCT; ++ct) {
        float bv = bias[ct * 16 + cl];
#pragma unroll
        for (int rt = 0; rt < 2; ++rt) acc[rt][ct] = (f32x4){bv, bv, bv, bv};
    }
    const _Float16* fb = frag + (size_t)l * 8;
#pragma unroll 1
    for (int ks = 0; ks < KSTEPS; ++ks) {
        v8h a0 = *(const v8h*)&buf[w * 32 + cl][ks * 32 + gl * 8];
        v8h a1 = *(const v8h*)&buf[w * 32 + 16 + cl][ks * 32 + gl * 8];
#pragma unroll
        for (int ct = 0; ct < NCT; ++ct) {
            v8h bf = *(const v8h*)(fb + (size_t)(ks * NCT + ct) * 512);
            acc[0][ct] = __builtin_amdgcn_mfma_f32_16x16x32_f16(a0, bf, acc[0][ct], 0, 0, 0);
            acc[1][ct] = __builtin_amdgcn_mfma_f32_16x16x32_f16(a1, bf, acc[1][ct], 0, 0, 0);
        }
    }
    // C/D layout (m89-verified): row=(l>>4)*4+j, col=l&15
#pragma unroll
    for (int rt = 0; rt < 2; ++rt)
#pragma unroll
        for (int ct = 0; ct < NCT; ++ct)
#pragma unroll
            for (int j = 0; j < 4; ++j) {
                float v = acc[rt][ct][j];
                if (RELU) v = fmaxf(v, 0.0f);
                buf[w * 32 + rt * 16 + gl * 4 + j][ct * 16 + cl] = (_Float16)v;
            }
}

// Block = 128 rows (16 queries x 8 NB), 4 waves, each wave owns 32 rows.
__global__ __launch_bounds__(256, 3) void mlp_kernel(
    const float* __restrict__ vf, const float4* __restrict__ vtx4,
    const float* __restrict__ qpts,
    const int* __restrict__ kidx, const float* __restrict__ kw,
    const _Float16* __restrict__ wfrag,
    const float* __restrict__ b0, const float* __restrict__ b1,
    const float* __restrict__ b2, const float* __restrict__ b3,
    float* __restrict__ out) {
    __shared__ _Float16 buf[128][136];
    const int tid = threadIdx.x, w = tid >> 6, l = tid & 63;
    {
        int h = l & 1;
        int lrow = w * 32 + (l >> 1);
        int grow = blockIdx.x * 128 + lrow;
        int q = grow >> 3;
        int idx = kidx[grow];
        const float4* src = (const float4*)(vf + (size_t)idx * DF) + h * 8;
#pragma unroll
        for (int t = 0; t < 4; ++t) {
            float4 a = src[2 * t], b = src[2 * t + 1];
            v8h pk = {(_Float16)a.x, (_Float16)a.y, (_Float16)a.z, (_Float16)a.w,
                      (_Float16)b.x, (_Float16)b.y, (_Float16)b.z, (_Float16)b.w};
            *(v8h*)&buf[lrow][h * 32 + t * 8] = pk;
        }
        v8h zz = {0, 0, 0, 0, 0, 0, 0, 0};
        if (h == 0) {
            float4 v = vtx4[idx];
            float qx = qpts[q * 3 + 0], qy = qpts[q * 3 + 1], qz = qpts[q * 3 + 2];
            v8h d = {(_Float16)(qx - v.x), (_Float16)(qy - v.y), (_Float16)(qz - v.z),
                     0, 0, 0, 0, 0};
            *(v8h*)&buf[lrow][64] = d;
            *(v8h*)&buf[lrow][88] = zz;
        } else {
            *(v8h*)&buf[lrow][72] = zz;
            *(v8h*)&buf[lrow][80] = zz;
        }
    }

    mlp_layer<3, 8, true>(buf, wfrag + 0,     b0, w, l);
    mlp_layer<4, 8, true>(buf, wfrag + 12288, b1, w, l);
    mlp_layer<4, 8, true>(buf, wfrag + 28672, b2, w, l);

    {
        const int cl = l & 15, gl = l >> 4;
        f32x4 acc[2][4];
#pragma unroll
        for (int ct = 0; ct < 4; ++ct) {
            float bv = b3[ct * 16 + cl];
#pragma unroll
            for (int rt = 0; rt < 2; ++rt) acc[rt][ct] = (f32x4){bv, bv, bv, bv};
        }
        const _Float16* fb = wfrag + 45056 + (size_t)l * 8;
#pragma unroll 1
        for (int ks = 0; ks < 4; ++ks) {
            v8h a0 = *(const v8h*)&buf[w * 32 + cl][ks * 32 + gl * 8];
            v8h a1 = *(const v8h*)&buf[w * 32 + 16 + cl][ks * 32 + gl * 8];
#pragma unroll
            for (int ct = 0; ct < 4; ++ct) {
                v8h bf = *(const v8h*)(fb + (size_t)(ks * 4 + ct) * 512);
                acc[0][ct] = __builtin_amdgcn_mfma_f32_16x16x32_f16(a0, bf, acc[0][ct], 0, 0, 0);
                acc[1][ct] = __builtin_amdgcn_mfma_f32_16x16x32_f16(a1, bf, acc[1][ct], 0, 0, 0);
            }
        }
        int GRbase = blockIdx.x * 128 + w * 32;
#pragma unroll
        for (int rt = 0; rt < 2; ++rt) {
            int r4 = GRbase + rt * 16 + gl * 4;
            float4 kv = *(const float4*)&kw[r4];
#pragma unroll
            for (int ct = 0; ct < 4; ++ct) {
                float v = acc[rt][ct][0] * kv.x + acc[rt][ct][1] * kv.y +
                          acc[rt][ct][2] * kv.z + acc[rt][ct][3] * kv.w;
                v += __shfl_xor(v, 16);
                if ((gl & 1) == 0) {
                    int q = (GRbase + rt * 16 + ((gl == 2) ? 8 : 0)) >> 3;
                    out[(size_t)q * 64 + ct * 16 + cl] = v;
                }
            }
        }
    }
}

extern "C" void kernel_launch(void* const* d_in, const int* in_sizes, int n_in,
                              void* d_out, int out_size, void* d_ws, size_t ws_size,
                              hipStream_t stream) {
    const float* vtx = (const float*)d_in[0];
    const float* vf  = (const float*)d_in[1];
    const float* qp  = (const float*)d_in[2];
    const float* W0  = (const float*)d_in[3];
    const float* b0  = (const float*)d_in[4];
    const float* W1  = (const float*)d_in[5];
    const float* b1  = (const float*)d_in[6];
    const float* W2  = (const float*)d_in[7];
    const float* b2  = (const float*)d_in[8];
    const float* W3  = (const float*)d_in[9];
    const float* b3  = (const float*)d_in[10];
    float*       out = (float*)d_out;

    char*     ws      = (char*)d_ws;
    float4*   vtx4    = (float4*)(ws + VTX4_OFF);
    u32*      vstart  = (u32*)(ws + VSTART_OFF);
    u32*      vcur    = (u32*)(ws + VCUR_OFF);
    u32*      qstart  = (u32*)(ws + QSTART_OFF);
    u32*      qcur    = (u32*)(ws + QCUR_OFF);
    float4*   vsorted = (float4*)(ws + VSORT_OFF);
    u32*      vsid    = (u32*)(ws + VSID_OFF);
    float4*   qsorted = (float4*)(ws + QSORT_OFF);
    int*      kidx    = (int*)(ws + KIDX_OFF);
    float*    kw      = (float*)(ws + KW_OFF);
    _Float16* wfrag   = (_Float16*)(ws + WFRAG_OFF);

    hipMemsetAsync(ws + VSTART_OFF, 0, (NC + 1) * 4, stream);
    hipMemsetAsync(ws + QSTART_OFF, 0, (NC + 1) * 4, stream);

    hipLaunchKernelGGL(prep_kernel, dim3(363), dim3(256), 0, stream,
                       vtx, vtx4, vstart, qstart, qp, W0, W1, W2, W3, wfrag);
    hipLaunchKernelGGL(scan_kernel, dim3(1), dim3(1024), 0, stream,
                       vstart, vcur, qstart, qcur);
    hipLaunchKernelGGL(scatter_kernel, dim3(155), dim3(256), 0, stream,
                       vtx, qp, vcur, qcur, vsorted, vsid, qsorted);
    hipLaunchKernelGGL(knn_kernel, dim3(NQ / 256), dim3(256), 0, stream,
                       vsorted, vsid, vstart, qsorted, kidx, kw);
    hipLaunchKernelGGL(mlp_kernel, dim3(NQ * 8 / 128), dim3(256), 0, stream,
                       vf, vtx4, qp, kidx, kw, wfrag, b0, b1, b2, b3, out);
}

// Round 13
// 189.071 us; speedup vs baseline: 8.6179x; 8.6179x over previous
//
#include <hip/hip_runtime.h>
#include <hip/hip_fp16.h>

#define NV    6890
#define NQ    32768
#define DF    64
#define NW    16      // waves per knn block
#define CHUNK 431     // ceil(NV/16)
#define SAMP  32      // sample vertices per wave (16*32 = 512 total)
#define CAPQ  20

typedef _Float16 v8h  __attribute__((ext_vector_type(8)));
typedef float    f32x4 __attribute__((ext_vector_type(4)));
typedef unsigned int       u32;
typedef unsigned long long u64;
typedef unsigned short     u16;

// ---- workspace layout (bytes) ----
static constexpr size_t VTX4_OFF  = 0;                               // float4[6912]
static constexpr size_t KIDX_OFF  = 110592;                          // int[NQ*8]
static constexpr size_t KW_OFF    = KIDX_OFF + (size_t)NQ * 8 * 4;   // float[NQ*8]
static constexpr size_t WFRAG_OFF = KW_OFF + (size_t)NQ * 8 * 4;     // f16[53248]

__device__ __forceinline__ u32 monof(float s) {
    u32 u = __float_as_uint(s);
    return (u & 0x80000000u) ? ~u : (u | 0x80000000u);
}

// distance-only sorted top-8 insert (ascending), ~24 VALU.
#define DINSERT(sv) do {                                               \
    bool c0 = (sv) < dbest[0], c1 = (sv) < dbest[1],                   \
         c2 = (sv) < dbest[2], c3 = (sv) < dbest[3],                   \
         c4 = (sv) < dbest[4], c5 = (sv) < dbest[5],                   \
         c6 = (sv) < dbest[6], c7 = (sv) < dbest[7];                   \
    dbest[7] = c7 ? (c6 ? dbest[6] : (sv)) : dbest[7];                 \
    dbest[6] = c6 ? (c5 ? dbest[5] : (sv)) : dbest[6];                 \
    dbest[5] = c5 ? (c4 ? dbest[4] : (sv)) : dbest[5];                 \
    dbest[4] = c4 ? (c3 ? dbest[3] : (sv)) : dbest[4];                 \
    dbest[3] = c3 ? (c2 ? dbest[2] : (sv)) : dbest[3];                 \
    dbest[2] = c2 ? (c1 ? dbest[1] : (sv)) : dbest[2];                 \
    dbest[1] = c1 ? (c0 ? dbest[0] : (sv)) : dbest[1];                 \
    dbest[0] = c0 ? (sv) : dbest[0];                                   \
} while (0)

// u64 sorted top-8 insert (ascending). Compares precomputed; uses OLD values.
#define KINSERT(nk) do {                                  \
    bool c0 = (nk) < key[0], c1 = (nk) < key[1],          \
         c2 = (nk) < key[2], c3 = (nk) < key[3],          \
         c4 = (nk) < key[4], c5 = (nk) < key[5],          \
         c6 = (nk) < key[6], c7 = (nk) < key[7];          \
    key[7] = c7 ? (c6 ? key[6] : (nk)) : key[7];          \
    key[6] = c6 ? (c5 ? key[5] : (nk)) : key[6];          \
    key[5] = c5 ? (c4 ? key[4] : (nk)) : key[5];          \
    key[4] = c4 ? (c3 ? key[3] : (nk)) : key[4];          \
    key[3] = c3 ? (c2 ? key[2] : (nk)) : key[3];          \
    key[2] = c2 ? (c1 ? key[1] : (nk)) : key[2];          \
    key[1] = c1 ? (c0 ? key[0] : (nk)) : key[1];          \
    key[0] = c0 ? (nk) : key[0];                          \
} while (0)

#define TRYQ(sv, jv) do {                                                      \
    if ((sv) <= T) {                                                           \
        if (cnt < CAPQ) { qq[w][l][cnt] = (u16)(jv); ++cnt; }                  \
        else {                                                                 \
            u64 nk = ((u64)monof(sv) << 16) | (u64)(jv);                       \
            if (nk < key[7]) { KINSERT(nk); }                                  \
        }                                                                      \
    }                                                                          \
} while (0)

// prep: pack vertices {x,y,z,0.5|v|^2} + pre-swizzle weights into MFMA frag
// order. Fragment map: tile t=kt*NCT+ct, elem=t*512+lane*8+j,
// k=kt*32+(lane>>4)*8+j, col=ct*16+(lane&15).
__global__ void prep_kernel(const float* __restrict__ vtx, float4* __restrict__ vtx4,
                            const float* __restrict__ W0, const float* __restrict__ W1,
                            const float* __restrict__ W2, const float* __restrict__ W3,
                            _Float16* __restrict__ wfrag) {
    int b = blockIdx.x;
    if (b < 27) {
        int i = b * 256 + threadIdx.x;
        if (i < NV) {
            float x = vtx[i * 3 + 0], y = vtx[i * 3 + 1], z = vtx[i * 3 + 2];
            vtx4[i] = make_float4(x, y, z, 0.5f * (x * x + y * y + z * z));
        }
        return;
    }
    int e = (b - 27) * 256 + threadIdx.x;   // 0..53247
    const float* W; int base, NCT, C, KD;
    if      (e < 12288) { W = W0; base = 0;     NCT = 8; C = 128; KD = 67;  }
    else if (e < 28672) { W = W1; base = 12288; NCT = 8; C = 128; KD = 128; }
    else if (e < 45056) { W = W2; base = 28672; NCT = 8; C = 128; KD = 128; }
    else                { W = W3; base = 45056; NCT = 4; C = 64;  KD = 128; }
    int le = e - base;
    int t = le >> 9, r = le & 511;
    int lane = r >> 3, j = r & 7;
    int kt = t / NCT, ct = t % NCT;
    int k = kt * 32 + (lane >> 4) * 8 + j;
    int col = ct * 16 + (lane & 15);
    float v = (k < KD) ? W[k * C + col] : 0.0f;
    wfrag[e] = (_Float16)v;
}

__device__ __forceinline__ float vdist(const float4 v, float nqx, float nqy, float nqz) {
    float s = fmaf(nqx, v.x, v.w);
    s = fmaf(nqy, v.y, s);
    return fmaf(nqz, v.z, s);
}

// Exact two-phase KNN, rebalanced. Block = 64 queries (1/lane) x 16 waves.
// Phase A (all waves): distance-only top-8 over a 32-vertex sample slice ->
//   LDS tree reduce (4 levels, disjoint slots) -> exact T = 8th smallest of
//   the 512-sample, broadcast to all waves.
// Scan (all waves): chunk of 431 vertices, unroll-4 wave-uniform float4 loads
//   (batched s_load), filter s<=T into per-lane u16 queue (cap 20; overflow ->
//   inline exact u64-key insert). Sample vertices are re-scanned (no exclusion
//   needed; survivors superset of true top-8 since T >= true d8).
// Drain: batches of 4, exact u64 keys. Merge: log2 tree over 16 lists.
// Key = (monotone(s)<<16)|idx reproduces top_k (distance,index) order.
__global__ __launch_bounds__(1024, 8) void knn_kernel(const float4* __restrict__ vtx4,
                                                      const float* __restrict__ qpts,
                                                      int* __restrict__ kidx,
                                                      float* __restrict__ kw) {
    __shared__ u64   kbuf[8][64][9];        // 36864 B; aliased as f32[16][64][9] in phase A
    __shared__ u16   qq[NW][64][CAPQ];      // 40960 B
    __shared__ float Tbc[64];
    float (*fbuf)[64][9] = (float (*)[64][9])kbuf;

    const int tid = threadIdx.x, w = tid >> 6, l = tid & 63;
    const int m = blockIdx.x * 64 + l;
    const float qx = qpts[m * 3 + 0], qy = qpts[m * 3 + 1], qz = qpts[m * 3 + 2];
    const float nqx = -qx, nqy = -qy, nqz = -qz;

    // ---- phase A: per-wave 32-vertex sample, distance-only top-8 ----
    float dbest[8];
#pragma unroll
    for (int i = 0; i < 8; ++i) dbest[i] = 3.0e38f;
    {
        const int s0 = w * SAMP;
#pragma unroll 4
        for (int j = s0; j < s0 + SAMP; ++j) {
            float s = vdist(vtx4[j], nqx, nqy, nqz);   // wave-uniform -> s_load
            DINSERT(s);
        }
    }
#pragma unroll
    for (int i = 0; i < 8; ++i) fbuf[w][l][i] = dbest[i];
    __syncthreads();

    // ---- T tree-reduce: read [st,2st) slots, merge into regs, write [0,st) ----
#pragma unroll 1
    for (int st = 8; st >= 1; st >>= 1) {
        if (w < st) {
#pragma unroll
            for (int e = 0; e < 8; ++e) {
                float s = fbuf[w + st][l][e];
                if (s < dbest[7]) { DINSERT(s); }
            }
            if (st > 1) {
#pragma unroll
                for (int i = 0; i < 8; ++i) fbuf[w][l][i] = dbest[i];
            }
        }
        __syncthreads();
    }
    if (w == 0) Tbc[l] = dbest[7];
    __syncthreads();
    const float T = Tbc[l];

    // ---- scan: full chunk, unroll-4, filter into queue ----
    u64 key[8];
#pragma unroll
    for (int i = 0; i < 8; ++i) key[i] = ~0ull;
    u32 cnt = 0;
    {
        const int j0 = w * CHUNK;
        const int j1 = (j0 + CHUNK < NV) ? j0 + CHUNK : NV;
        int j = j0;
#pragma unroll 1
        for (; j + 4 <= j1; j += 4) {
            float4 v0 = vtx4[j], v1 = vtx4[j + 1], v2 = vtx4[j + 2], v3 = vtx4[j + 3];
            float s0 = vdist(v0, nqx, nqy, nqz);
            float s1 = vdist(v1, nqx, nqy, nqz);
            float s2 = vdist(v2, nqx, nqy, nqz);
            float s3 = vdist(v3, nqx, nqy, nqz);
            TRYQ(s0, j); TRYQ(s1, j + 1); TRYQ(s2, j + 2); TRYQ(s3, j + 3);
        }
        for (; j < j1; ++j) {
            float s = vdist(vtx4[j], nqx, nqy, nqz);
            TRYQ(s, j);
        }
    }

    // ---- drain queue in batches of 4 (exact keys) ----
#pragma unroll 1
    for (int b = 0; b < CAPQ; b += 4) {
        if (!__any(cnt > (u32)b)) break;
        u32 jj[4]; float4 vv[4];
#pragma unroll
        for (int t = 0; t < 4; ++t) {
            u32 qi = ((u32)(b + t) < cnt) ? (u32)qq[w][l][b + t] : 0u;
            jj[t] = qi; vv[t] = vtx4[qi];
        }
#pragma unroll
        for (int t = 0; t < 4; ++t) {
            float s = vdist(vv[t], nqx, nqy, nqz);
            u64 nk = ((u64)monof(s) << 16) | (u64)jj[t];
            nk = ((u32)(b + t) < cnt) ? nk : ~0ull;
            if (nk < key[7]) { KINSERT(nk); }
        }
    }

    // ---- tree merge of 16 key lists: publish [st,2st) -> merge on [0,st) ----
#pragma unroll 1
    for (int st = 8; st >= 1; st >>= 1) {
        if (w >= st && w < 2 * st) {
#pragma unroll
            for (int i = 0; i < 8; ++i) kbuf[w - st][l][i] = key[i];
        }
        __syncthreads();
        if (w < st) {
#pragma unroll
            for (int e = 0; e < 8; ++e) {
                u64 nk = kbuf[w][l][e];
                if (nk < key[7]) { KINSERT(nk); }
            }
        }
        __syncthreads();
    }

    // ---- wave 0: weights + output ----
    if (w == 0) {
        float q2 = fmaf(qx, qx, fmaf(qy, qy, qz * qz));
        float inv[8], ssum = 0.0f;
        int idx8[8];
#pragma unroll
        for (int i = 0; i < 8; ++i) {
            u32 us = (u32)(key[i] >> 16);
            u32 uo = (us & 0x80000000u) ? (us & 0x7FFFFFFFu) : ~us;
            float s = __uint_as_float(uo);
            float dd = fmaf(2.0f, s, q2);
            float d = sqrtf(fmaxf(dd, 0.0f)) + 1e-9f;
            inv[i] = 1.0f / d; ssum += inv[i];
            idx8[i] = (int)(key[i] & 0xFFFFull);
        }
        float rs = 1.0f / ssum;
#pragma unroll
        for (int i = 0; i < 8; ++i) {
            kidx[m * 8 + i] = idx8[i];
            kw[m * 8 + i]   = inv[i] * rs;
        }
    }
}

// One MLP layer on this wave's 32 rows, in-place in buf. A-frag: row=l&15(+16*rt),
// k=(l>>4)*8+j; B-frag preswizzled with the SAME (lane,j)->k map (k-perm cancels).
template <int KSTEPS, int NCT, bool RELU>
__device__ __forceinline__ void mlp_layer(_Float16 (*buf)[136],
                                          const _Float16* __restrict__ frag,
                                          const float* __restrict__ bias,
                                          int w, int l) {
    const int cl = l & 15, gl = l >> 4;
    f32x4 acc[2][NCT];
#pragma unroll
    for (int ct = 0; ct < NCT; ++ct) {
        float bv = bias[ct * 16 + cl];
#pragma unroll
        for (int rt = 0; rt < 2; ++rt) acc[rt][ct] = (f32x4){bv, bv, bv, bv};
    }
    const _Float16* fb = frag + (size_t)l * 8;
#pragma unroll 1
    for (int ks = 0; ks < KSTEPS; ++ks) {
        v8h a0 = *(const v8h*)&buf[w * 32 + cl][ks * 32 + gl * 8];
        v8h a1 = *(const v8h*)&buf[w * 32 + 16 + cl][ks * 32 + gl * 8];
#pragma unroll
        for (int ct = 0; ct < NCT; ++ct) {
            v8h bf = *(const v8h*)(fb + (size_t)(ks * NCT + ct) * 512);
            acc[0][ct] = __builtin_amdgcn_mfma_f32_16x16x32_f16(a0, bf, acc[0][ct], 0, 0, 0);
            acc[1][ct] = __builtin_amdgcn_mfma_f32_16x16x32_f16(a1, bf, acc[1][ct], 0, 0, 0);
        }
    }
    // C/D layout (m89-verified): row=(l>>4)*4+j, col=l&15
#pragma unroll
    for (int rt = 0; rt < 2; ++rt)
#pragma unroll
        for (int ct = 0; ct < NCT; ++ct)
#pragma unroll
            for (int j = 0; j < 4; ++j) {
                float v = acc[rt][ct][j];
                if (RELU) v = fmaxf(v, 0.0f);
                buf[w * 32 + rt * 16 + gl * 4 + j][ct * 16 + cl] = (_Float16)v;
            }
}

// Block = 128 rows (16 queries x 8 NB), 4 waves, each wave owns 32 rows.
__global__ __launch_bounds__(256, 3) void mlp_kernel(
    const float* __restrict__ vf, const float4* __restrict__ vtx4,
    const float* __restrict__ qpts,
    const int* __restrict__ kidx, const float* __restrict__ kw,
    const _Float16* __restrict__ wfrag,
    const float* __restrict__ b0, const float* __restrict__ b1,
    const float* __restrict__ b2, const float* __restrict__ b3,
    float* __restrict__ out) {
    __shared__ _Float16 buf[128][136];
    const int tid = threadIdx.x, w = tid >> 6, l = tid & 63;
    {
        int h = l & 1;
        int lrow = w * 32 + (l >> 1);
        int grow = blockIdx.x * 128 + lrow;
        int q = grow >> 3;
        int idx = kidx[grow];
        const float4* src = (const float4*)(vf + (size_t)idx * DF) + h * 8;
#pragma unroll
        for (int t = 0; t < 4; ++t) {
            float4 a = src[2 * t], b = src[2 * t + 1];
            v8h pk = {(_Float16)a.x, (_Float16)a.y, (_Float16)a.z, (_Float16)a.w,
                      (_Float16)b.x, (_Float16)b.y, (_Float16)b.z, (_Float16)b.w};
            *(v8h*)&buf[lrow][h * 32 + t * 8] = pk;
        }
        v8h zz = {0, 0, 0, 0, 0, 0, 0, 0};
        if (h == 0) {
            float4 v = vtx4[idx];
            float qx = qpts[q * 3 + 0], qy = qpts[q * 3 + 1], qz = qpts[q * 3 + 2];
            v8h d = {(_Float16)(qx - v.x), (_Float16)(qy - v.y), (_Float16)(qz - v.z),
                     0, 0, 0, 0, 0};
            *(v8h*)&buf[lrow][64] = d;
            *(v8h*)&buf[lrow][88] = zz;
        } else {
            *(v8h*)&buf[lrow][72] = zz;
            *(v8h*)&buf[lrow][80] = zz;
        }
    }

    mlp_layer<3, 8, true>(buf, wfrag + 0,     b0, w, l);
    mlp_layer<4, 8, true>(buf, wfrag + 12288, b1, w, l);
    mlp_layer<4, 8, true>(buf, wfrag + 28672, b2, w, l);

    {
        const int cl = l & 15, gl = l >> 4;
        f32x4 acc[2][4];
#pragma unroll
        for (int ct = 0; ct < 4; ++ct) {
            float bv = b3[ct * 16 + cl];
#pragma unroll
            for (int rt = 0; rt < 2; ++rt) acc[rt][ct] = (f32x4){bv, bv, bv, bv};
        }
        const _Float16* fb = wfrag + 45056 + (size_t)l * 8;
#pragma unroll 1
        for (int ks = 0; ks < 4; ++ks) {
            v8h a0 = *(const v8h*)&buf[w * 32 + cl][ks * 32 + gl * 8];
            v8h a1 = *(const v8h*)&buf[w * 32 + 16 + cl][ks * 32 + gl * 8];
#pragma unroll
            for (int ct = 0; ct < 4; ++ct) {
                v8h bf = *(const v8h*)(fb + (size_t)(ks * 4 + ct) * 512);
                acc[0][ct] = __builtin_amdgcn_mfma_f32_16x16x32_f16(a0, bf, acc[0][ct], 0, 0, 0);
                acc[1][ct] = __builtin_amdgcn_mfma_f32_16x16x32_f16(a1, bf, acc[1][ct], 0, 0, 0);
            }
        }
        int GRbase = blockIdx.x * 128 + w * 32;
#pragma unroll
        for (int rt = 0; rt < 2; ++rt) {
            int r4 = GRbase + rt * 16 + gl * 4;
            float4 kv = *(const float4*)&kw[r4];
#pragma unroll
            for (int ct = 0; ct < 4; ++ct) {
                float v = acc[rt][ct][0] * kv.x + acc[rt][ct][1] * kv.y +
                          acc[rt][ct][2] * kv.z + acc[rt][ct][3] * kv.w;
                v += __shfl_xor(v, 16);
                if ((gl & 1) == 0) {
                    int q = (GRbase + rt * 16 + ((gl == 2) ? 8 : 0)) >> 3;
                    out[(size_t)q * 64 + ct * 16 + cl] = v;
                }
            }
        }
    }
}

extern "C" void kernel_launch(void* const* d_in, const int* in_sizes, int n_in,
                              void* d_out, int out_size, void* d_ws, size_t ws_size,
                              hipStream_t stream) {
    const float* vtx = (const float*)d_in[0];
    const float* vf  = (const float*)d_in[1];
    const float* qp  = (const float*)d_in[2];
    const float* W0  = (const float*)d_in[3];
    const float* b0  = (const float*)d_in[4];
    const float* W1  = (const float*)d_in[5];
    const float* b1  = (const float*)d_in[6];
    const float* W2  = (const float*)d_in[7];
    const float* b2  = (const float*)d_in[8];
    const float* W3  = (const float*)d_in[9];
    const float* b3  = (const float*)d_in[10];
    float*       out = (float*)d_out;

    char*      ws    = (char*)d_ws;
    float4*    vtx4  = (float4*)(ws + VTX4_OFF);
    int*       kidx  = (int*)(ws + KIDX_OFF);
    float*     kw    = (float*)(ws + KW_OFF);
    _Float16*  wfrag = (_Float16*)(ws + WFRAG_OFF);

    hipLaunchKernelGGL(prep_kernel, dim3(27 + 208), dim3(256), 0, stream,
                       vtx, vtx4, W0, W1, W2, W3, wfrag);
    hipLaunchKernelGGL(knn_kernel, dim3(NQ / 64), dim3(1024), 0, stream, vtx4, qp, kidx, kw);
    hipLaunchKernelGGL(mlp_kernel, dim3(NQ * 8 / 128), dim3(256), 0, stream,
                       vf, vtx4, qp, kidx, kw, wfrag, b0, b1, b2, b3, out);
}